// Round 2
// baseline (6637.936 us; speedup 1.0000x reference)
//
#include <hip/hip_runtime.h>
#include <math.h>

#define H 300
#define H3 900
#define NAt 16385
#define NBd 65537
#define NM 256
#define APM 64

// ======================= fp32 tiled GEMM (128x128, 8x8 micro) =======================
// GATHER: A row r is (A[idx1[r]] - A2[idx2[r]]) -- fused bond-message update.
// W2: also store result to C2 (used to init message_bond = input_bond).
template<bool ACCUM, bool ADDMAT, bool BIAS, bool RELU, bool GATHER, bool W2>
__global__ __launch_bounds__(256) void gemm_f32(
    const float* __restrict__ A, const float* __restrict__ A2,
    const int* __restrict__ idx1, const int* __restrict__ idx2,
    const float* __restrict__ B,
    float* __restrict__ C, float* __restrict__ C2,
    const float* __restrict__ D, const float* __restrict__ bias,
    int M, int N, int K, int lda, int ldb, int ldc)
{
  __shared__ float As[16][128];
  __shared__ float Bs[16][128];
  const int tid = threadIdx.x;
  const int m0 = blockIdx.y * 128;
  const int n0 = blockIdx.x * 128;
  const int tx = tid & 15;
  const int ty = tid >> 4;
  float acc[8][8];
#pragma unroll
  for (int i = 0; i < 8; i++)
#pragma unroll
    for (int j = 0; j < 8; j++) acc[i][j] = 0.f;

  const int lar = tid >> 1;        // A row within tile (0..127)
  const int lak = (tid & 1) * 8;   // A k offset (0 or 8)
  const int lbn = tid & 127;       // B col within tile
  const int lbk = tid >> 7;        // B k base (0 or 1)

  const int gr = m0 + lar;
  const bool rok = gr < M;
  const float* Ap;
  const float* Ap2 = nullptr;
  if constexpr (GATHER) {
    int r1 = rok ? idx1[gr] : 0;
    int r2 = rok ? idx2[gr] : 0;
    Ap  = A  + (size_t)r1 * lda;
    Ap2 = A2 + (size_t)r2 * lda;
  } else {
    Ap = A + (size_t)gr * lda;
  }

  for (int k0 = 0; k0 < K; k0 += 16) {
    {
#pragma unroll
      for (int i = 0; i < 8; i++) {
        int gk = k0 + lak + i;
        float v = 0.f;
        if (rok && gk < K) {
          v = Ap[gk];
          if constexpr (GATHER) v -= Ap2[gk];
        }
        As[lak + i][lar] = v;
      }
    }
    {
      int gn = n0 + lbn;
#pragma unroll
      for (int i = 0; i < 8; i++) {
        int kk = lbk + i * 2;
        int gk = k0 + kk;
        Bs[kk][lbn] = (gk < K && gn < N) ? B[(size_t)gk * ldb + gn] : 0.f;
      }
    }
    __syncthreads();
#pragma unroll
    for (int kk = 0; kk < 16; kk++) {
      float4 a0 = *(const float4*)&As[kk][ty * 8];
      float4 a1 = *(const float4*)&As[kk][ty * 8 + 4];
      float4 b0 = *(const float4*)&Bs[kk][tx * 8];
      float4 b1 = *(const float4*)&Bs[kk][tx * 8 + 4];
      float av[8] = {a0.x, a0.y, a0.z, a0.w, a1.x, a1.y, a1.z, a1.w};
      float bv[8] = {b0.x, b0.y, b0.z, b0.w, b1.x, b1.y, b1.z, b1.w};
#pragma unroll
      for (int i = 0; i < 8; i++)
#pragma unroll
        for (int j = 0; j < 8; j++)
          acc[i][j] = fmaf(av[i], bv[j], acc[i][j]);
    }
    __syncthreads();
  }

#pragma unroll
  for (int i = 0; i < 8; i++) {
    int gm = m0 + ty * 8 + i;
    if (gm >= M) continue;
    size_t rowoff = (size_t)gm * ldc;
#pragma unroll
    for (int j = 0; j < 8; j++) {
      int gn = n0 + tx * 8 + j;
      if (gn >= N) continue;
      float v = acc[i][j];
      if constexpr (ADDMAT) v += D[rowoff + gn];
      if constexpr (BIAS) v += bias[gn];
      if constexpr (ACCUM) v += C[rowoff + gn];
      if constexpr (RELU) v = fmaxf(v, 0.f);
      C[rowoff + gn] = v;
      if constexpr (W2) C2[rowoff + gn] = v;
    }
  }
}

// ======================= neighbor aggregation: sum * max over 6 =======================
template<bool UPDATE>
__global__ __launch_bounds__(256) void agg_kernel(
    const float* __restrict__ message_bond, const int* __restrict__ a2b,
    float* __restrict__ out)
{
  int gid = blockIdx.x * 256 + threadIdx.x;
  if (gid >= NAt * H) return;
  int a = gid / H;
  int hh = gid - a * H;
  const int* ab = a2b + (size_t)a * 6;
  float s = 0.f, mx = -3.0e38f;
#pragma unroll
  for (int j = 0; j < 6; j++) {
    float v = message_bond[(size_t)ab[j] * H + hh];
    s += v;
    mx = fmaxf(mx, v);
  }
  float agg = s * mx;
  if (UPDATE) out[gid] += agg;
  else out[gid] = agg;
}

// ======================= misc elementwise =======================
__global__ __launch_bounds__(256) void msg_kernel(
    const float* __restrict__ node, const float* __restrict__ gru_bias,
    float* __restrict__ msg)
{
  int gid = blockIdx.x * 256 + threadIdx.x;
  if (gid >= NAt * H) return;
  int hh = gid % H;
  msg[gid] = fmaxf(node[gid] + gru_bias[hh], 0.f);
}

__global__ __launch_bounds__(256) void h0_kernel(
    const float* __restrict__ node, float* __restrict__ h0)
{
  int gid = blockIdx.x * 256 + threadIdx.x;
  if (gid >= NM * H) return;
  int m = gid / H;
  int hh = gid - m * H;
  const float* base = node + ((size_t)(1 + m * APM)) * H + hh;
  float mx = base[0];
  for (int t = 1; t < APM; t++) mx = fmaxf(mx, base[(size_t)t * H]);
  h0[gid] = mx;
}

__global__ __launch_bounds__(256) void transpose_kernel(
    const float* __restrict__ w, float* __restrict__ wT)
{
  int gid = blockIdx.x * 256 + threadIdx.x;
  if (gid >= H * H3) return;
  int k = gid / H3;
  int g = gid - k * H3;
  wT[gid] = w[(size_t)g * H + k];  // wT[k][g] = w[g][k]
}

__global__ __launch_bounds__(256) void row0_kernel(
    const float* __restrict__ msg, float* __restrict__ message)
{
  int gid = blockIdx.x * 256 + threadIdx.x;
  if (gid >= 2 * H) return;
  message[gid] = msg[gid % H];
}

__global__ __launch_bounds__(256) void mean_kernel(
    const float* __restrict__ ah, float* __restrict__ out)
{
  int gid = blockIdx.x * 256 + threadIdx.x;
  if (gid >= NM * H) return;
  int m = gid / H;
  int hh = gid - m * H;
  const float* base = ah + ((size_t)(1 + m * APM)) * H + hh;
  float s = 0.f;
#pragma unroll 8
  for (int t = 0; t < APM; t++) s += base[(size_t)t * H];
  out[gid] = s * (1.f / APM);
}

// ======================= GRU step =======================
// grid = 256 blocks: blockIdx.x -> ct (col tile 0..3), mg (mol group 0..31), dir (0..1)
// Each block recomputes h_cur for its 8 mols from (gates_prev, h_prev) [ping-pong slots],
// then computes its 225-col slice of h_cur @ w_hh^T + b_hh into the write slot.
__global__ __launch_bounds__(256) void gru_step_kernel(
    const float* __restrict__ xg_f, const float* __restrict__ xg_b,
    const float* __restrict__ w_hh_f, const float* __restrict__ w_hh_b,
    const float* __restrict__ b_hh_f, const float* __restrict__ b_hh_b,
    const float* __restrict__ h0,
    float* __restrict__ h_buf,   // [2][2][NM][H]
    float* __restrict__ g_buf,   // [2][2][NM][H3]
    float* __restrict__ message, // [NAt][600]
    int s)
{
  __shared__ float h_lds[8 * H];
  const int tid = threadIdx.x;
  const int b = blockIdx.x;
  const int ct = b & 3;
  const int mg = (b >> 2) & 31;
  const int dir = b >> 7;
  const int r = s & 1;
  const int w = 1 - r;
  const float* xg = dir ? xg_b : xg_f;
  const float* whh = dir ? w_hh_b : w_hh_f;
  const float* bhh = dir ? b_hh_b : b_hh_f;
  const float* hb_r = h_buf + ((size_t)(r * 2 + dir)) * NM * H;
  float* hb_w = h_buf + ((size_t)(w * 2 + dir)) * NM * H;
  const float* gb_r = g_buf + ((size_t)(r * 2 + dir)) * NM * H3;
  float* gb_w = g_buf + ((size_t)(w * 2 + dir)) * NM * H3;

  int t_prev = 0;
  if (s > 0) t_prev = dir ? (64 - s) : (s - 1);

  // phase 1: h_cur for this block's 8 mols
  for (int i = tid; i < 8 * H; i += 256) {
    int m = i / H;
    int hh = i - m * H;
    int mol = mg * 8 + m;
    float hc;
    if (s == 0) {
      hc = h0[(size_t)mol * H + hh];
    } else {
      const float* xr = xg + ((size_t)(mol * 64 + t_prev)) * H3;
      float ir = xr[hh], iz = xr[H + hh], inn = xr[2 * H + hh];
      const float* gp = gb_r + (size_t)mol * H3;
      float hr = gp[hh], hz = gp[H + hh], hn = gp[2 * H + hh];
      float hp = hb_r[(size_t)mol * H + hh];
      float rr = 1.f / (1.f + expf(-(ir + hr)));
      float zz = 1.f / (1.f + expf(-(iz + hz)));
      float nn = tanhf(inn + rr * hn);
      hc = (1.f - zz) * nn + zz * hp;
    }
    h_lds[i] = hc;
    if (ct == 0) {
      hb_w[(size_t)mol * H + hh] = hc;
      if (s > 0) {
        int row = 1 + mol * 64 + t_prev;
        message[(size_t)row * 600 + dir * H + hh] = hc;
      }
    }
  }
  __syncthreads();
  if (s >= 64) return;

  // phase 2: gate slice [ct*225, (ct+1)*225)
  for (int i = tid; i < 8 * 225; i += 256) {
    int m = i & 7;
    int gl = i >> 3;
    int g = ct * 225 + gl;
    const float4* wr4 = (const float4*)(whh + (size_t)g * H);
    const float4* hl4 = (const float4*)(h_lds + m * H);
    float acc = bhh[g];
#pragma unroll 5
    for (int k = 0; k < H / 4; k++) {
      float4 wv = wr4[k];
      float4 hv = hl4[k];
      acc += wv.x * hv.x + wv.y * hv.y + wv.z * hv.z + wv.w * hv.w;
    }
    int mol = mg * 8 + m;
    gb_w[(size_t)mol * H3 + g] = acc;
  }
}

// ======================= host =======================
// Workspace layout (floats), total 63,898,800 floats = 255.6 MB:
//   [0, 19661100)            ib  (input_bond)           -> later xgf (14,745,600)
//   [19661100, 39322200)     mb0 (bond msg ping)        -> later message(9,831,000) + h0/wT/hbuf/gbuf
//   [39322200, 58983300)     mb1 (bond msg pong)        -> later aggb/node/iat, msg tail, then xgb
//   [58983300, 63898800)     ma  (message_atom)         -> later ah
extern "C" void kernel_launch(void* const* d_in, const int* in_sizes, int n_in,
                              void* d_out, int out_size, void* d_ws, size_t ws_size,
                              hipStream_t stream) {
  (void)in_sizes; (void)n_in; (void)out_size; (void)ws_size;
  const float* f_atoms  = (const float*)d_in[0];
  const float* f_bonds  = (const float*)d_in[1];
  const int*   a2b      = (const int*)d_in[2];
  const int*   b2a      = (const int*)d_in[3];
  const int*   b2revb   = (const int*)d_in[4];
  const float* W_i_atom = (const float*)d_in[5];
  const float* W_i_bond = (const float*)d_in[6];
  const float* W_h      = (const float*)d_in[7];
  const float* W_lr     = (const float*)d_in[8];
  const float* W_o      = (const float*)d_in[9];
  const float* b_o      = (const float*)d_in[10];
  const float* gru_bias = (const float*)d_in[11];
  const float* w_ih_f   = (const float*)d_in[12];
  const float* w_hh_f   = (const float*)d_in[13];
  const float* b_ih_f   = (const float*)d_in[14];
  const float* b_hh_f   = (const float*)d_in[15];
  const float* w_ih_b   = (const float*)d_in[16];
  const float* w_hh_b   = (const float*)d_in[17];
  const float* b_ih_b   = (const float*)d_in[18];
  const float* b_hh_b   = (const float*)d_in[19];

  float* ws = (float*)d_ws;
  const size_t SZ_B = (size_t)NBd * H;  // 19,661,100
  const size_t SZ_A = (size_t)NAt * H;  //  4,915,500

  float* ib  = ws;
  float* mb0 = ws + SZ_B;
  float* mb1 = ws + 2 * SZ_B;
  float* ma  = ws + 3 * SZ_B;
  // late-phase aliases (all reuse regions dead by the time they're written)
  float* xgf     = ib;                        // 14,745,600
  float* message = mb0;                       //  9,831,000
  float* h0      = mb0 + 9831000;             //     76,800
  float* wTf     = h0 + (size_t)NM * H;       //    270,000
  float* wTb     = wTf + (size_t)H * H3;      //    270,000
  float* hbuf    = wTb + (size_t)H * H3;      //    307,200
  float* gbuf    = hbuf + (size_t)4 * NM * H; //    921,600
  float* aggb    = mb1;                       //  4,915,500
  float* node    = mb1 + SZ_A;                //  4,915,500
  float* iat     = mb1 + 2 * SZ_A;            //  4,915,500 (recomputed input_atom)
  float* msg     = mb1 + 14745600;            //  4,915,500 (exactly fills mb1 tail)
  float* xgb     = mb1;                       // 14,745,600 (after aggb/node/iat dead)
  float* ah      = ma;                        //  4,915,500 (after ma dead)

  dim3 blk(256);
  auto gg = [](int M, int N) {
    return dim3((unsigned)((N + 127) / 128), (unsigned)((M + 127) / 128));
  };
  const int gA = (int)((SZ_A + 255) / 256);

  // ma = input_atom = relu(f_atoms @ W_i_atom)   (message_atom init)
  gemm_f32<false,false,false,true,false,false><<<gg(NAt, H), blk, 0, stream>>>(
      f_atoms, nullptr, nullptr, nullptr, W_i_atom, ma, nullptr, nullptr, nullptr,
      NAt, H, 133, 133, H, H);
  // ib = input_bond = relu(f_bonds @ W_i_bond); mb0 = copy (message_bond init)
  gemm_f32<false,false,false,true,false,true><<<gg(NBd, H), blk, 0, stream>>>(
      f_bonds, nullptr, nullptr, nullptr, W_i_bond, ib, mb0, nullptr, nullptr,
      NBd, H, 147, 147, H, H);

  // message passing depth loop (ping-pong mb0<->mb1, bond update fused into GEMM A-load)
  float* mbp[2] = {mb0, mb1};
  int cur = 0;
  for (int d = 0; d < 4; d++) {
    agg_kernel<true><<<gA, blk, 0, stream>>>(mbp[cur], a2b, ma);
    gemm_f32<false,true,false,true,true,false><<<gg(NBd, H), blk, 0, stream>>>(
        ma, mbp[cur], b2a, b2revb, W_h + (size_t)d * H * H,
        mbp[1 - cur], nullptr, ib, nullptr, NBd, H, H, H, H, H);
    cur ^= 1;
  }
  // cur == 0 again: final message_bond is in mb0
  agg_kernel<false><<<gA, blk, 0, stream>>>(mb0, a2b, aggb);

  // node = [agg | message_atom | input_atom] @ W_lr  (3 accumulating GEMMs)
  gemm_f32<false,false,false,false,false,false><<<gg(NAt, H), blk, 0, stream>>>(
      aggb, nullptr, nullptr, nullptr, W_lr, node, nullptr, nullptr, nullptr,
      NAt, H, H, H, H, H);
  gemm_f32<true,false,false,false,false,false><<<gg(NAt, H), blk, 0, stream>>>(
      ma, nullptr, nullptr, nullptr, W_lr + (size_t)H * H, node, nullptr, nullptr, nullptr,
      NAt, H, H, H, H, H);
  gemm_f32<false,false,false,true,false,false><<<gg(NAt, H), blk, 0, stream>>>(
      f_atoms, nullptr, nullptr, nullptr, W_i_atom, iat, nullptr, nullptr, nullptr,
      NAt, H, 133, 133, H, H);  // recompute input_atom
  gemm_f32<true,false,false,false,false,false><<<gg(NAt, H), blk, 0, stream>>>(
      iat, nullptr, nullptr, nullptr, W_lr + (size_t)2 * H * H, node, nullptr, nullptr, nullptr,
      NAt, H, H, H, H, H);

  h0_kernel<<<(NM * H + 255) / 256, blk, 0, stream>>>(node, h0);
  msg_kernel<<<gA, blk, 0, stream>>>(node, gru_bias, msg);

  // GRU input gates: xg = xs @ w_ih^T + b_ih  (pre-transpose w_ih)
  const int gT = (H * H3 + 255) / 256;
  transpose_kernel<<<gT, blk, 0, stream>>>(w_ih_f, wTf);
  transpose_kernel<<<gT, blk, 0, stream>>>(w_ih_b, wTb);
  gemm_f32<false,false,true,false,false,false><<<gg(16384, H3), blk, 0, stream>>>(
      msg + H, nullptr, nullptr, nullptr, wTf, xgf, nullptr, nullptr, b_ih_f,
      16384, H3, H, H, H3, H3);
  gemm_f32<false,false,true,false,false,false><<<gg(16384, H3), blk, 0, stream>>>(
      msg + H, nullptr, nullptr, nullptr, wTb, xgb, nullptr, nullptr, b_ih_b,
      16384, H3, H, H, H3, H3);

  // sequential bidirectional GRU: 65 step launches (step 64 = final update only)
  for (int s = 0; s <= 64; s++) {
    gru_step_kernel<<<256, blk, 0, stream>>>(
        xgf, xgb, w_hh_f, w_hh_b, b_hh_f, b_hh_b, h0, hbuf, gbuf, message, s);
  }
  row0_kernel<<<3, blk, 0, stream>>>(msg, message);

  // readout
  gemm_f32<false,false,true,true,false,false><<<gg(NAt, H), blk, 0, stream>>>(
      message, nullptr, nullptr, nullptr, W_o, ah, nullptr, nullptr, b_o,
      NAt, H, 600, 600, H, H);
  mean_kernel<<<(NM * H + 255) / 256, blk, 0, stream>>>(ah, (float*)d_out);
}

// Round 4
// 5557.065 us; speedup vs baseline: 1.1945x; 1.1945x over previous
//
#include <hip/hip_runtime.h>
#include <math.h>

#define H 300
#define H3 900
#define NAt 16385
#define NBd 65537
#define NM 256
#define APM 64

typedef __attribute__((ext_vector_type(8))) short bf16x8;
typedef __attribute__((ext_vector_type(4))) float f32x4;

__device__ __forceinline__ unsigned bf16_rne(float x) {
  unsigned u = __float_as_uint(x);
  return (u + 0x7fffu + ((u >> 16) & 1u)) >> 16;
}
__device__ __forceinline__ float bf16_up(unsigned h) {
  return __uint_as_float(h << 16);
}
// 3-way split: x ~= h + m + l (each bf16), residual ~2^-26 |x|
__device__ __forceinline__ void split3(float x, unsigned &h, unsigned &m, unsigned &l) {
  h = bf16_rne(x);
  float r1 = x - bf16_up(h);
  m = bf16_rne(r1);
  float r2 = r1 - bf16_up(m);
  l = bf16_rne(r2);
}

// ======================= triple-split bf16 MFMA GEMM =======================
// C[M,N] = A[M,K] @ B[K,N], fp32 in/out. Each operand split 3-way in bf16;
// product via 6 MFMAs (hh + hm + mh + mm + hl + lh), residual ~2^-25 --
// fp32-class accuracy at bf16-MFMA/6 rate (~400 TF ceiling).
// BM=128, BN=64, BK=32; 4 waves, each 64x32 (4x2 tiles of 16x16x32).
// A and B staged in LDS in MFMA fragment order: 16B granule per (tile,lane),
// lane = (row&15) | (koct<<4) -- conflict-free b128 reads and writes.
// GATHER: A row r = A[idx1[r]] - A2[idx2[r]] (fused bond-message update).
// W2: duplicate store to C2.
template<bool ACCUM, bool ADDMAT, bool BIAS, bool RELU, bool GATHER, bool W2>
__global__ __launch_bounds__(256) void gemm_mfma(
    const float* __restrict__ A, const float* __restrict__ A2,
    const int* __restrict__ idx1, const int* __restrict__ idx2,
    const float* __restrict__ B,
    float* __restrict__ C, float* __restrict__ C2,
    const float* __restrict__ D, const float* __restrict__ bias,
    int M, int N, int K, int lda, int ldb, int ldc)
{
  __shared__ uint4 sA[3][512];  // [split][8 m-tiles * 64 lanes]
  __shared__ uint4 sB[3][256];  // [split][4 n-tiles * 64 lanes]

  const int tid = threadIdx.x;
  const int m0 = blockIdx.y * 128;
  const int n0 = blockIdx.x * 64;

  // staging roles
  const int a_koct = tid & 3;        // k-octet 0..3
  const int a_m = tid >> 2;          // row 0..63 (items: a_m, a_m+64)
  const int b_n = tid & 63;          // col 0..63
  const int b_koct = tid >> 6;       // k-octet 0..3

  const float* Arow[2];
  const float* Arow2[2] = {nullptr, nullptr};
  bool arok[2];
#pragma unroll
  for (int it = 0; it < 2; it++) {
    int gm = m0 + a_m + it * 64;
    arok[it] = gm < M;
    if constexpr (GATHER) {
      int i1 = arok[it] ? idx1[gm] : 0;
      int i2 = arok[it] ? idx2[gm] : 0;
      Arow[it] = A + (size_t)i1 * lda;
      Arow2[it] = A2 + (size_t)i2 * lda;
    } else {
      Arow[it] = A + (size_t)(arok[it] ? gm : 0) * lda;
    }
  }
  const int gn_b = n0 + b_n;
  const bool bnok = gn_b < N;

  const int lane = tid & 63;
  const int wid = tid >> 6;
  const int wr = wid >> 1;   // wave row (0..1)
  const int wc = wid & 1;    // wave col (0..1)

  f32x4 acc[4][2];
#pragma unroll
  for (int i = 0; i < 4; i++)
#pragma unroll
    for (int j = 0; j < 2; j++) acc[i][j] = (f32x4){0.f, 0.f, 0.f, 0.f};

  const int KT = (K + 31) >> 5;
  for (int kt = 0; kt < KT; kt++) {
    const int k0 = kt << 5;
    // ---- stage A (2 items/thread) ----
#pragma unroll
    for (int it = 0; it < 2; it++) {
      const int m = a_m + it * 64;
      const int kb = k0 + a_koct * 8;
      float x[8];
#pragma unroll
      for (int j = 0; j < 8; j++) {
        int gk = kb + j;
        float v = 0.f;
        if (arok[it] && gk < K) {
          v = Arow[it][gk];
          if constexpr (GATHER) v -= Arow2[it][gk];
        }
        x[j] = v;
      }
      unsigned h[8], mm_[8], l[8];
#pragma unroll
      for (int j = 0; j < 8; j++) split3(x[j], h[j], mm_[j], l[j]);
      uint4 hv, mv, lv;
      hv.x = h[0] | (h[1] << 16);   hv.y = h[2] | (h[3] << 16);
      hv.z = h[4] | (h[5] << 16);   hv.w = h[6] | (h[7] << 16);
      mv.x = mm_[0] | (mm_[1] << 16); mv.y = mm_[2] | (mm_[3] << 16);
      mv.z = mm_[4] | (mm_[5] << 16); mv.w = mm_[6] | (mm_[7] << 16);
      lv.x = l[0] | (l[1] << 16);   lv.y = l[2] | (l[3] << 16);
      lv.z = l[4] | (l[5] << 16);   lv.w = l[6] | (l[7] << 16);
      const int fi = ((m >> 4) << 6) | (m & 15) | (a_koct << 4);
      sA[0][fi] = hv;
      sA[1][fi] = mv;
      sA[2][fi] = lv;
    }
    // ---- stage B (1 item/thread) ----
    {
      const int kb = k0 + b_koct * 8;
      float x[8];
#pragma unroll
      for (int j = 0; j < 8; j++) {
        int gk = kb + j;
        x[j] = (bnok && gk < K) ? B[(size_t)gk * ldb + gn_b] : 0.f;
      }
      unsigned h[8], mm_[8], l[8];
#pragma unroll
      for (int j = 0; j < 8; j++) split3(x[j], h[j], mm_[j], l[j]);
      uint4 hv, mv, lv;
      hv.x = h[0] | (h[1] << 16);   hv.y = h[2] | (h[3] << 16);
      hv.z = h[4] | (h[5] << 16);   hv.w = h[6] | (h[7] << 16);
      mv.x = mm_[0] | (mm_[1] << 16); mv.y = mm_[2] | (mm_[3] << 16);
      mv.z = mm_[4] | (mm_[5] << 16); mv.w = mm_[6] | (mm_[7] << 16);
      lv.x = l[0] | (l[1] << 16);   lv.y = l[2] | (l[3] << 16);
      lv.z = l[4] | (l[5] << 16);   lv.w = l[6] | (l[7] << 16);
      const int fi = ((b_n >> 4) << 6) | (b_n & 15) | (b_koct << 4);
      sB[0][fi] = hv;
      sB[1][fi] = mv;
      sB[2][fi] = lv;
    }
    __syncthreads();
    // ---- compute: 6 MFMAs per tile pair, small terms first ----
    bf16x8 aF[3][4], bF[3][2];
#pragma unroll
    for (int p = 0; p < 3; p++)
#pragma unroll
      for (int i = 0; i < 4; i++) {
        const int fi = ((wr * 4 + i) << 6) | lane;
        aF[p][i] = ((const bf16x8*)sA[p])[fi];
      }
#pragma unroll
    for (int p = 0; p < 3; p++)
#pragma unroll
      for (int j = 0; j < 2; j++) {
        const int fi = ((wc * 2 + j) << 6) | lane;
        bF[p][j] = ((const bf16x8*)sB[p])[fi];
      }
#pragma unroll
    for (int i = 0; i < 4; i++)
#pragma unroll
      for (int j = 0; j < 2; j++) {
        acc[i][j] = __builtin_amdgcn_mfma_f32_16x16x32_bf16(aF[2][i], bF[0][j], acc[i][j], 0, 0, 0);
        acc[i][j] = __builtin_amdgcn_mfma_f32_16x16x32_bf16(aF[0][i], bF[2][j], acc[i][j], 0, 0, 0);
        acc[i][j] = __builtin_amdgcn_mfma_f32_16x16x32_bf16(aF[1][i], bF[1][j], acc[i][j], 0, 0, 0);
        acc[i][j] = __builtin_amdgcn_mfma_f32_16x16x32_bf16(aF[1][i], bF[0][j], acc[i][j], 0, 0, 0);
        acc[i][j] = __builtin_amdgcn_mfma_f32_16x16x32_bf16(aF[0][i], bF[1][j], acc[i][j], 0, 0, 0);
        acc[i][j] = __builtin_amdgcn_mfma_f32_16x16x32_bf16(aF[0][i], bF[0][j], acc[i][j], 0, 0, 0);
      }
    __syncthreads();
  }

  // ---- epilogue: C/D layout col=lane&15, row=(lane>>4)*4+r ----
  const int cr = (lane >> 4) << 2;
  const int cc = lane & 15;
#pragma unroll
  for (int i = 0; i < 4; i++) {
#pragma unroll
    for (int r = 0; r < 4; r++) {
      const int gm = m0 + wr * 64 + i * 16 + cr + r;
      if (gm >= M) continue;
      const size_t rowoff = (size_t)gm * ldc;
#pragma unroll
      for (int j = 0; j < 2; j++) {
        const int gn = n0 + wc * 32 + j * 16 + cc;
        if (gn >= N) continue;
        float v = acc[i][j][r];
        if constexpr (ADDMAT) v += D[rowoff + gn];
        if constexpr (BIAS) v += bias[gn];
        if constexpr (ACCUM) v += C[rowoff + gn];
        if constexpr (RELU) v = fmaxf(v, 0.f);
        C[rowoff + gn] = v;
        if constexpr (W2) C2[rowoff + gn] = v;
      }
    }
  }
}

// ======================= neighbor aggregation: sum * max over 6 =======================
template<bool UPDATE>
__global__ __launch_bounds__(256) void agg_kernel(
    const float* __restrict__ message_bond, const int* __restrict__ a2b,
    float* __restrict__ out)
{
  int gid = blockIdx.x * 256 + threadIdx.x;
  if (gid >= NAt * H) return;
  int a = gid / H;
  int hh = gid - a * H;
  const int* ab = a2b + (size_t)a * 6;
  float s = 0.f, mx = -3.0e38f;
#pragma unroll
  for (int j = 0; j < 6; j++) {
    float v = message_bond[(size_t)ab[j] * H + hh];
    s += v;
    mx = fmaxf(mx, v);
  }
  float agg = s * mx;
  if (UPDATE) out[gid] += agg;
  else out[gid] = agg;
}

// ======================= misc elementwise =======================
__global__ __launch_bounds__(256) void msg_kernel(
    const float* __restrict__ node, const float* __restrict__ gru_bias,
    float* __restrict__ msg)
{
  int gid = blockIdx.x * 256 + threadIdx.x;
  if (gid >= NAt * H) return;
  int hh = gid % H;
  msg[gid] = fmaxf(node[gid] + gru_bias[hh], 0.f);
}

__global__ __launch_bounds__(256) void h0_kernel(
    const float* __restrict__ node, float* __restrict__ h0)
{
  int gid = blockIdx.x * 256 + threadIdx.x;
  if (gid >= NM * H) return;
  int m = gid / H;
  int hh = gid - m * H;
  const float* base = node + ((size_t)(1 + m * APM)) * H + hh;
  float mx = base[0];
  for (int t = 1; t < APM; t++) mx = fmaxf(mx, base[(size_t)t * H]);
  h0[gid] = mx;
}

__global__ __launch_bounds__(256) void transpose_kernel(
    const float* __restrict__ w, float* __restrict__ wT)
{
  int gid = blockIdx.x * 256 + threadIdx.x;
  if (gid >= H * H3) return;
  int k = gid / H3;
  int g = gid - k * H3;
  wT[gid] = w[(size_t)g * H + k];  // wT[k][g] = w[g][k]
}

__global__ __launch_bounds__(256) void row0_kernel(
    const float* __restrict__ msg, float* __restrict__ message)
{
  int gid = blockIdx.x * 256 + threadIdx.x;
  if (gid >= 2 * H) return;
  message[gid] = msg[gid % H];
}

__global__ __launch_bounds__(256) void mean_kernel(
    const float* __restrict__ ah, float* __restrict__ out)
{
  int gid = blockIdx.x * 256 + threadIdx.x;
  if (gid >= NM * H) return;
  int m = gid / H;
  int hh = gid - m * H;
  const float* base = ah + ((size_t)(1 + m * APM)) * H + hh;
  float s = 0.f;
#pragma unroll 8
  for (int t = 0; t < APM; t++) s += base[(size_t)t * H];
  out[gid] = s * (1.f / APM);
}

// ======================= GRU step =======================
__global__ __launch_bounds__(256) void gru_step_kernel(
    const float* __restrict__ xg_f, const float* __restrict__ xg_b,
    const float* __restrict__ w_hh_f, const float* __restrict__ w_hh_b,
    const float* __restrict__ b_hh_f, const float* __restrict__ b_hh_b,
    const float* __restrict__ h0,
    float* __restrict__ h_buf,   // [2][2][NM][H]
    float* __restrict__ g_buf,   // [2][2][NM][H3]
    float* __restrict__ message, // [NAt][600]
    int s)
{
  __shared__ float h_lds[8 * H];
  const int tid = threadIdx.x;
  const int b = blockIdx.x;
  const int ct = b & 3;
  const int mg = (b >> 2) & 31;
  const int dir = b >> 7;
  const int r = s & 1;
  const int w = 1 - r;
  const float* xg = dir ? xg_b : xg_f;
  const float* whh = dir ? w_hh_b : w_hh_f;
  const float* bhh = dir ? b_hh_b : b_hh_f;
  const float* hb_r = h_buf + ((size_t)(r * 2 + dir)) * NM * H;
  float* hb_w = h_buf + ((size_t)(w * 2 + dir)) * NM * H;
  const float* gb_r = g_buf + ((size_t)(r * 2 + dir)) * NM * H3;
  float* gb_w = g_buf + ((size_t)(w * 2 + dir)) * NM * H3;

  int t_prev = 0;
  if (s > 0) t_prev = dir ? (64 - s) : (s - 1);

  // phase 1: h_cur for this block's 8 mols
  for (int i = tid; i < 8 * H; i += 256) {
    int m = i / H;
    int hh = i - m * H;
    int mol = mg * 8 + m;
    float hc;
    if (s == 0) {
      hc = h0[(size_t)mol * H + hh];
    } else {
      const float* xr = xg + ((size_t)(mol * 64 + t_prev)) * H3;
      float ir = xr[hh], iz = xr[H + hh], inn = xr[2 * H + hh];
      const float* gp = gb_r + (size_t)mol * H3;
      float hr = gp[hh], hz = gp[H + hh], hn = gp[2 * H + hh];
      float hp = hb_r[(size_t)mol * H + hh];
      float rr = 1.f / (1.f + expf(-(ir + hr)));
      float zz = 1.f / (1.f + expf(-(iz + hz)));
      float nn = tanhf(inn + rr * hn);
      hc = (1.f - zz) * nn + zz * hp;
    }
    h_lds[i] = hc;
    if (ct == 0) {
      hb_w[(size_t)mol * H + hh] = hc;
      if (s > 0) {
        int row = 1 + mol * 64 + t_prev;
        message[(size_t)row * 600 + dir * H + hh] = hc;
      }
    }
  }
  __syncthreads();
  if (s >= 64) return;

  // phase 2: gate slice [ct*225, (ct+1)*225)
  for (int i = tid; i < 8 * 225; i += 256) {
    int m = i & 7;
    int gl = i >> 3;
    int g = ct * 225 + gl;
    const float4* wr4 = (const float4*)(whh + (size_t)g * H);
    const float4* hl4 = (const float4*)(h_lds + m * H);
    float acc = bhh[g];
#pragma unroll 5
    for (int k = 0; k < H / 4; k++) {
      float4 wv = wr4[k];
      float4 hv = hl4[k];
      acc += wv.x * hv.x + wv.y * hv.y + wv.z * hv.z + wv.w * hv.w;
    }
    int mol = mg * 8 + m;
    gb_w[(size_t)mol * H3 + g] = acc;
  }
}

// ======================= host =======================
// Workspace layout (floats), total 63,898,800 floats = 255.6 MB (see round-1 notes).
extern "C" void kernel_launch(void* const* d_in, const int* in_sizes, int n_in,
                              void* d_out, int out_size, void* d_ws, size_t ws_size,
                              hipStream_t stream) {
  (void)in_sizes; (void)n_in; (void)out_size; (void)ws_size;
  const float* f_atoms  = (const float*)d_in[0];
  const float* f_bonds  = (const float*)d_in[1];
  const int*   a2b      = (const int*)d_in[2];
  const int*   b2a      = (const int*)d_in[3];
  const int*   b2revb   = (const int*)d_in[4];
  const float* W_i_atom = (const float*)d_in[5];
  const float* W_i_bond = (const float*)d_in[6];
  const float* W_h      = (const float*)d_in[7];
  const float* W_lr     = (const float*)d_in[8];
  const float* W_o      = (const float*)d_in[9];
  const float* b_o      = (const float*)d_in[10];
  const float* gru_bias = (const float*)d_in[11];
  const float* w_ih_f   = (const float*)d_in[12];
  const float* w_hh_f   = (const float*)d_in[13];
  const float* b_ih_f   = (const float*)d_in[14];
  const float* b_hh_f   = (const float*)d_in[15];
  const float* w_ih_b   = (const float*)d_in[16];
  const float* w_hh_b   = (const float*)d_in[17];
  const float* b_ih_b   = (const float*)d_in[18];
  const float* b_hh_b   = (const float*)d_in[19];

  float* ws = (float*)d_ws;
  const size_t SZ_B = (size_t)NBd * H;  // 19,661,100
  const size_t SZ_A = (size_t)NAt * H;  //  4,915,500

  float* ib  = ws;
  float* mb0 = ws + SZ_B;
  float* mb1 = ws + 2 * SZ_B;
  float* ma  = ws + 3 * SZ_B;
  // late-phase aliases (all reuse regions dead by the time they're written)
  float* xgf     = ib;                        // 14,745,600
  float* message = mb0;                       //  9,831,000
  float* h0      = mb0 + 9831000;             //     76,800
  float* wTf     = h0 + (size_t)NM * H;       //    270,000
  float* wTb     = wTf + (size_t)H * H3;      //    270,000
  float* hbuf    = wTb + (size_t)H * H3;      //    307,200
  float* gbuf    = hbuf + (size_t)4 * NM * H; //    921,600
  float* aggb    = mb1;                       //  4,915,500
  float* node    = mb1 + SZ_A;                //  4,915,500
  float* iat     = mb1 + 2 * SZ_A;            //  4,915,500 (recomputed input_atom)
  float* msg     = mb1 + 14745600;            //  4,915,500 (exactly fills mb1 tail)
  float* xgb     = mb1;                       // 14,745,600 (after aggb/node/iat dead)
  float* ah      = ma;                        //  4,915,500 (after ma dead)

  dim3 blk(256);
  auto gg = [](int M, int N) {
    return dim3((unsigned)((N + 63) / 64), (unsigned)((M + 127) / 128));
  };
  const int gA = (int)((SZ_A + 255) / 256);

  // ma = input_atom = relu(f_atoms @ W_i_atom)   (message_atom init)
  gemm_mfma<false,false,false,true,false,false><<<gg(NAt, H), blk, 0, stream>>>(
      f_atoms, nullptr, nullptr, nullptr, W_i_atom, ma, nullptr, nullptr, nullptr,
      NAt, H, 133, 133, H, H);
  // ib = input_bond = relu(f_bonds @ W_i_bond); mb0 = copy (message_bond init)
  gemm_mfma<false,false,false,true,false,true><<<gg(NBd, H), blk, 0, stream>>>(
      f_bonds, nullptr, nullptr, nullptr, W_i_bond, ib, mb0, nullptr, nullptr,
      NBd, H, 147, 147, H, H);

  // message passing depth loop (ping-pong mb0<->mb1, bond update fused into GEMM A-load)
  float* mbp[2] = {mb0, mb1};
  int cur = 0;
  for (int d = 0; d < 4; d++) {
    agg_kernel<true><<<gA, blk, 0, stream>>>(mbp[cur], a2b, ma);
    gemm_mfma<false,true,false,true,true,false><<<gg(NBd, H), blk, 0, stream>>>(
        ma, mbp[cur], b2a, b2revb, W_h + (size_t)d * H * H,
        mbp[1 - cur], nullptr, ib, nullptr, NBd, H, H, H, H, H);
    cur ^= 1;
  }
  // cur == 0 again: final message_bond is in mb0
  agg_kernel<false><<<gA, blk, 0, stream>>>(mb0, a2b, aggb);

  // node = [agg | message_atom | input_atom] @ W_lr  (3 accumulating GEMMs)
  gemm_mfma<false,false,false,false,false,false><<<gg(NAt, H), blk, 0, stream>>>(
      aggb, nullptr, nullptr, nullptr, W_lr, node, nullptr, nullptr, nullptr,
      NAt, H, H, H, H, H);
  gemm_mfma<true,false,false,false,false,false><<<gg(NAt, H), blk, 0, stream>>>(
      ma, nullptr, nullptr, nullptr, W_lr + (size_t)H * H, node, nullptr, nullptr, nullptr,
      NAt, H, H, H, H, H);
  gemm_mfma<false,false,false,true,false,false><<<gg(NAt, H), blk, 0, stream>>>(
      f_atoms, nullptr, nullptr, nullptr, W_i_atom, iat, nullptr, nullptr, nullptr,
      NAt, H, 133, 133, H, H);  // recompute input_atom
  gemm_mfma<true,false,false,false,false,false><<<gg(NAt, H), blk, 0, stream>>>(
      iat, nullptr, nullptr, nullptr, W_lr + (size_t)2 * H * H, node, nullptr, nullptr, nullptr,
      NAt, H, H, H, H, H);

  h0_kernel<<<(NM * H + 255) / 256, blk, 0, stream>>>(node, h0);
  msg_kernel<<<gA, blk, 0, stream>>>(node, gru_bias, msg);

  // GRU input gates: xg = xs @ w_ih^T + b_ih  (pre-transpose w_ih)
  const int gT = (H * H3 + 255) / 256;
  transpose_kernel<<<gT, blk, 0, stream>>>(w_ih_f, wTf);
  transpose_kernel<<<gT, blk, 0, stream>>>(w_ih_b, wTb);
  gemm_mfma<false,false,true,false,false,false><<<gg(16384, H3), blk, 0, stream>>>(
      msg + H, nullptr, nullptr, nullptr, wTf, xgf, nullptr, nullptr, b_ih_f,
      16384, H3, H, H, H3, H3);
  gemm_mfma<false,false,true,false,false,false><<<gg(16384, H3), blk, 0, stream>>>(
      msg + H, nullptr, nullptr, nullptr, wTb, xgb, nullptr, nullptr, b_ih_b,
      16384, H3, H, H, H3, H3);

  // sequential bidirectional GRU: 65 step launches (step 64 = final update only)
  for (int s = 0; s <= 64; s++) {
    gru_step_kernel<<<256, blk, 0, stream>>>(
        xgf, xgb, w_hh_f, w_hh_b, b_hh_f, b_hh_b, h0, hbuf, gbuf, message, s);
  }
  row0_kernel<<<3, blk, 0, stream>>>(msg, message);

  // readout
  gemm_mfma<false,false,true,true,false,false><<<gg(NAt, H), blk, 0, stream>>>(
      message, nullptr, nullptr, nullptr, W_o, ah, nullptr, nullptr, b_o,
      NAt, H, 600, 600, H, H);
  mean_kernel<<<(NM * H + 255) / 256, blk, 0, stream>>>(ah, (float*)d_out);
}

// Round 5
// 4883.540 us; speedup vs baseline: 1.3592x; 1.1379x over previous
//
#include <hip/hip_runtime.h>
#include <math.h>

#define H 300
#define H3 900
#define NAt 16385
#define NBd 65537
#define NM 256
#define APM 64

typedef __attribute__((ext_vector_type(8))) short bf16x8;
typedef __attribute__((ext_vector_type(4))) float f32x4;

__device__ __forceinline__ unsigned bf16_rne(float x) {
  unsigned u = __float_as_uint(x);
  return (u + 0x7fffu + ((u >> 16) & 1u)) >> 16;
}
__device__ __forceinline__ float bf16_up(unsigned h) {
  return __uint_as_float(h << 16);
}
// 3-way split: x ~= h + m + l (each bf16), residual ~2^-26 |x|
__device__ __forceinline__ void split3(float x, unsigned &h, unsigned &m, unsigned &l) {
  h = bf16_rne(x);
  float r1 = x - bf16_up(h);
  m = bf16_rne(r1);
  float r2 = r1 - bf16_up(m);
  l = bf16_rne(r2);
}
__device__ __forceinline__ void pack8(const unsigned* v, uint4 &o) {
  o.x = v[0] | (v[1] << 16); o.y = v[2] | (v[3] << 16);
  o.z = v[4] | (v[5] << 16); o.w = v[6] | (v[7] << 16);
}

// ============== triple-split bf16 MFMA GEMM, full-N row stripes ==============
// C[M,N] = A[M,K] @ B[K,N], fp32 in/out, split3 + 6 MFMAs per tile pair.
// BM=64 rows, BN=320 cols (one col-block covers N<=320 -> A read exactly once).
// 4 waves: wave w owns n-tiles [5w,5w+5), all 4 m-tiles. BK=32 per k-step.
// LDS in MFMA fragment order (16B granule per (tile,lane)), conflict-free b128.
// GATHER: A row r = A[idx1[r]] - A2[idx2[r]] (fused bond-message update).
// CONCAT: A row r = [A[r] | A2[r] | A3[r]] along K (lda each, K=3*lda).
// W2: duplicate store to C2.
template<bool ADDMAT, bool BIAS, bool RELU, bool GATHER, bool CONCAT, bool W2>
__global__ __launch_bounds__(256, 2) void gemm_mfma2(
    const float* __restrict__ A, const float* __restrict__ A2,
    const float* __restrict__ A3,
    const int* __restrict__ idx1, const int* __restrict__ idx2,
    const float* __restrict__ B,
    float* __restrict__ C, float* __restrict__ C2,
    const float* __restrict__ D, const float* __restrict__ bias,
    int M, int N, int K, int lda, int ldb, int ldc)
{
  __shared__ uint4 sA[3][256];   // 4 m-tiles * 64 lanes
  __shared__ uint4 sB[3][1280];  // 20 n-tiles * 64 lanes

  const int tid = threadIdx.x;
  const int lane = tid & 63;
  const int wid = tid >> 6;
  const int m0 = blockIdx.y * 64;
  const int n0 = blockIdx.x * 320;
  int NTloc = (N - n0 + 15) >> 4;
  if (NTloc > 20) NTloc = 20;

  // A staging role: one 16B granule: m-tile = wid, row lane&15, koct lane>>4
  const int a_row = m0 + (wid << 4) + (lane & 15);
  const int a_koct = lane >> 4;
  const bool arok = a_row < M;
  const float* Ap = nullptr;
  const float* Ap2 = nullptr;
  const float* Ap3 = nullptr;
  if constexpr (GATHER) {
    int i1 = arok ? idx1[a_row] : 0;
    int i2 = arok ? idx2[a_row] : 0;
    Ap  = A  + (size_t)i1 * lda;
    Ap2 = A2 + (size_t)i2 * lda;
  } else if constexpr (CONCAT) {
    int r = arok ? a_row : 0;
    Ap  = A  + (size_t)r * lda;
    Ap2 = A2 + (size_t)r * lda;
    Ap3 = A3 + (size_t)r * lda;
  } else {
    Ap = A + (size_t)(arok ? a_row : 0) * lda;
  }

  f32x4 acc[4][5];
#pragma unroll
  for (int i = 0; i < 4; i++)
#pragma unroll
    for (int j = 0; j < 5; j++) acc[i][j] = (f32x4){0.f, 0.f, 0.f, 0.f};

  const int KT = (K + 31) >> 5;
  for (int kt = 0; kt < KT; kt++) {
    const int kb0 = kt << 5;
    // ---- stage A (1 granule/thread) ----
    {
      const int kb = kb0 + a_koct * 8;
      float x[8];
#pragma unroll
      for (int j = 0; j < 8; j++) {
        int gk = kb + j;
        float v = 0.f;
        if (arok && gk < K) {
          if constexpr (GATHER) {
            v = Ap[gk] - Ap2[gk];
          } else if constexpr (CONCAT) {
            int s_ = (gk >= 2 * lda) ? 2 : ((gk >= lda) ? 1 : 0);
            int col = gk - s_ * lda;
            const float* src = (s_ == 0) ? Ap : ((s_ == 1) ? Ap2 : Ap3);
            v = src[col];
          } else {
            v = Ap[gk];
          }
        }
        x[j] = v;
      }
      unsigned h[8], mv_[8], l[8];
#pragma unroll
      for (int j = 0; j < 8; j++) split3(x[j], h[j], mv_[j], l[j]);
      uint4 hv, mv, lv;
      pack8(h, hv); pack8(mv_, mv); pack8(l, lv);
      const int fi = (wid << 6) | lane;
      sA[0][fi] = hv; sA[1][fi] = mv; sA[2][fi] = lv;
    }
    // ---- stage B (5 granules/thread) ----
#pragma unroll
    for (int i = 0; i < 5; i++) {
      const int g = tid + (i << 8);
      const int t = g >> 6;
      if (t < NTloc) {
        const int gl = g & 63;
        const int n = n0 + (t << 4) + (gl & 15);
        const int kb = kb0 + ((gl >> 4) << 3);
        float x[8];
#pragma unroll
        for (int j = 0; j < 8; j++) {
          int gk = kb + j;
          x[j] = (n < N && gk < K) ? B[(size_t)gk * ldb + n] : 0.f;
        }
        unsigned h[8], mv_[8], l[8];
#pragma unroll
        for (int j = 0; j < 8; j++) split3(x[j], h[j], mv_[j], l[j]);
        uint4 hv, mv, lv;
        pack8(h, hv); pack8(mv_, mv); pack8(l, lv);
        sB[0][g] = hv; sB[1][g] = mv; sB[2][g] = lv;
      }
    }
    __syncthreads();
    // ---- compute: wave's 5 n-tiles x 4 m-tiles, 6 MFMAs each ----
    bf16x8 aF[3][4];
#pragma unroll
    for (int p = 0; p < 3; p++)
#pragma unroll
      for (int i = 0; i < 4; i++)
        aF[p][i] = ((const bf16x8*)sA[p])[(i << 6) | lane];
#pragma unroll
    for (int j = 0; j < 5; j++) {
      const int t = wid * 5 + j;
      if (t < NTloc) {
        const int fi = (t << 6) | lane;
        bf16x8 b0 = ((const bf16x8*)sB[0])[fi];
        bf16x8 b1 = ((const bf16x8*)sB[1])[fi];
        bf16x8 b2 = ((const bf16x8*)sB[2])[fi];
#pragma unroll
        for (int i = 0; i < 4; i++) {
          acc[i][j] = __builtin_amdgcn_mfma_f32_16x16x32_bf16(aF[2][i], b0, acc[i][j], 0, 0, 0);
          acc[i][j] = __builtin_amdgcn_mfma_f32_16x16x32_bf16(aF[0][i], b2, acc[i][j], 0, 0, 0);
          acc[i][j] = __builtin_amdgcn_mfma_f32_16x16x32_bf16(aF[1][i], b1, acc[i][j], 0, 0, 0);
          acc[i][j] = __builtin_amdgcn_mfma_f32_16x16x32_bf16(aF[1][i], b0, acc[i][j], 0, 0, 0);
          acc[i][j] = __builtin_amdgcn_mfma_f32_16x16x32_bf16(aF[0][i], b1, acc[i][j], 0, 0, 0);
          acc[i][j] = __builtin_amdgcn_mfma_f32_16x16x32_bf16(aF[0][i], b0, acc[i][j], 0, 0, 0);
        }
      }
    }
    __syncthreads();
  }

  // ---- epilogue: C/D layout col=lane&15, row=(lane>>4)*4+r ----
  const int cr = (lane >> 4) << 2;
  const int cc = lane & 15;
#pragma unroll
  for (int j = 0; j < 5; j++) {
    const int t = wid * 5 + j;
    if (t >= NTloc) break;
    const int gn = n0 + (t << 4) + cc;
    if (gn >= N) continue;
#pragma unroll
    for (int i = 0; i < 4; i++) {
#pragma unroll
      for (int r = 0; r < 4; r++) {
        const int gm = m0 + (i << 4) + cr + r;
        if (gm >= M) continue;
        const size_t rowoff = (size_t)gm * ldc;
        float v = acc[i][j][r];
        if constexpr (ADDMAT) v += D[rowoff + gn];
        if constexpr (BIAS) v += bias[gn];
        if constexpr (RELU) v = fmaxf(v, 0.f);
        C[rowoff + gn] = v;
        if constexpr (W2) C2[rowoff + gn] = v;
      }
    }
  }
}

// ======================= neighbor aggregation: sum * max over 6 =======================
template<bool UPDATE>
__global__ __launch_bounds__(256) void agg_kernel(
    const float* __restrict__ message_bond, const int* __restrict__ a2b,
    float* __restrict__ out)
{
  int gid = blockIdx.x * 256 + threadIdx.x;
  if (gid >= NAt * H) return;
  int a = gid / H;
  int hh = gid - a * H;
  const int* ab = a2b + (size_t)a * 6;
  float s = 0.f, mx = -3.0e38f;
#pragma unroll
  for (int j = 0; j < 6; j++) {
    float v = message_bond[(size_t)ab[j] * H + hh];
    s += v;
    mx = fmaxf(mx, v);
  }
  float agg = s * mx;
  if (UPDATE) out[gid] += agg;
  else out[gid] = agg;
}

// ======================= misc elementwise =======================
__global__ __launch_bounds__(256) void msg_kernel(
    const float* __restrict__ node, const float* __restrict__ gru_bias,
    float* __restrict__ msg)
{
  int gid = blockIdx.x * 256 + threadIdx.x;
  if (gid >= NAt * H) return;
  int hh = gid % H;
  msg[gid] = fmaxf(node[gid] + gru_bias[hh], 0.f);
}

__global__ __launch_bounds__(256) void h0_kernel(
    const float* __restrict__ node, float* __restrict__ h0)
{
  int gid = blockIdx.x * 256 + threadIdx.x;
  if (gid >= NM * H) return;
  int m = gid / H;
  int hh = gid - m * H;
  const float* base = node + ((size_t)(1 + m * APM)) * H + hh;
  float mx = base[0];
  for (int t = 1; t < APM; t++) mx = fmaxf(mx, base[(size_t)t * H]);
  h0[gid] = mx;
}

__global__ __launch_bounds__(256) void transpose_kernel(
    const float* __restrict__ w, float* __restrict__ wT)
{
  int gid = blockIdx.x * 256 + threadIdx.x;
  if (gid >= H * H3) return;
  int k = gid / H3;
  int g = gid - k * H3;
  wT[gid] = w[(size_t)g * H + k];  // wT[k][g] = w[g][k]
}

__global__ __launch_bounds__(256) void row0_kernel(
    const float* __restrict__ msg, float* __restrict__ message)
{
  int gid = blockIdx.x * 256 + threadIdx.x;
  if (gid >= 2 * H) return;
  message[gid] = msg[gid % H];
}

__global__ __launch_bounds__(256) void mean_kernel(
    const float* __restrict__ ah, float* __restrict__ out)
{
  int gid = blockIdx.x * 256 + threadIdx.x;
  if (gid >= NM * H) return;
  int m = gid / H;
  int hh = gid - m * H;
  const float* base = ah + ((size_t)(1 + m * APM)) * H + hh;
  float s = 0.f;
#pragma unroll 8
  for (int t = 0; t < APM; t++) s += base[(size_t)t * H];
  out[gid] = s * (1.f / APM);
}

// ======================= GRU step =======================
__global__ __launch_bounds__(256) void gru_step_kernel(
    const float* __restrict__ xg_f, const float* __restrict__ xg_b,
    const float* __restrict__ w_hh_f, const float* __restrict__ w_hh_b,
    const float* __restrict__ b_hh_f, const float* __restrict__ b_hh_b,
    const float* __restrict__ h0,
    float* __restrict__ h_buf,   // [2][2][NM][H]
    float* __restrict__ g_buf,   // [2][2][NM][H3]
    float* __restrict__ message, // [NAt][600]
    int s)
{
  __shared__ float h_lds[8 * H];
  const int tid = threadIdx.x;
  const int b = blockIdx.x;
  const int ct = b & 3;
  const int mg = (b >> 2) & 31;
  const int dir = b >> 7;
  const int r = s & 1;
  const int w = 1 - r;
  const float* xg = dir ? xg_b : xg_f;
  const float* whh = dir ? w_hh_b : w_hh_f;
  const float* bhh = dir ? b_hh_b : b_hh_f;
  const float* hb_r = h_buf + ((size_t)(r * 2 + dir)) * NM * H;
  float* hb_w = h_buf + ((size_t)(w * 2 + dir)) * NM * H;
  const float* gb_r = g_buf + ((size_t)(r * 2 + dir)) * NM * H3;
  float* gb_w = g_buf + ((size_t)(w * 2 + dir)) * NM * H3;

  int t_prev = 0;
  if (s > 0) t_prev = dir ? (64 - s) : (s - 1);

  // phase 1: h_cur for this block's 8 mols
  for (int i = tid; i < 8 * H; i += 256) {
    int m = i / H;
    int hh = i - m * H;
    int mol = mg * 8 + m;
    float hc;
    if (s == 0) {
      hc = h0[(size_t)mol * H + hh];
    } else {
      const float* xr = xg + ((size_t)(mol * 64 + t_prev)) * H3;
      float ir = xr[hh], iz = xr[H + hh], inn = xr[2 * H + hh];
      const float* gp = gb_r + (size_t)mol * H3;
      float hr = gp[hh], hz = gp[H + hh], hn = gp[2 * H + hh];
      float hp = hb_r[(size_t)mol * H + hh];
      float rr = 1.f / (1.f + expf(-(ir + hr)));
      float zz = 1.f / (1.f + expf(-(iz + hz)));
      float nn = tanhf(inn + rr * hn);
      hc = (1.f - zz) * nn + zz * hp;
    }
    h_lds[i] = hc;
    if (ct == 0) {
      hb_w[(size_t)mol * H + hh] = hc;
      if (s > 0) {
        int row = 1 + mol * 64 + t_prev;
        message[(size_t)row * 600 + dir * H + hh] = hc;
      }
    }
  }
  __syncthreads();
  if (s >= 64) return;

  // phase 2: gate slice [ct*225, (ct+1)*225)
  for (int i = tid; i < 8 * 225; i += 256) {
    int m = i & 7;
    int gl = i >> 3;
    int g = ct * 225 + gl;
    const float4* wr4 = (const float4*)(whh + (size_t)g * H);
    const float4* hl4 = (const float4*)(h_lds + m * H);
    float acc = bhh[g];
#pragma unroll 5
    for (int k = 0; k < H / 4; k++) {
      float4 wv = wr4[k];
      float4 hv = hl4[k];
      acc += wv.x * hv.x + wv.y * hv.y + wv.z * hv.z + wv.w * hv.w;
    }
    int mol = mg * 8 + m;
    gb_w[(size_t)mol * H3 + g] = acc;
  }
}

// ======================= host =======================
// Workspace layout (floats), total 63,898,800 floats = 255.6 MB (round-1 notes).
extern "C" void kernel_launch(void* const* d_in, const int* in_sizes, int n_in,
                              void* d_out, int out_size, void* d_ws, size_t ws_size,
                              hipStream_t stream) {
  (void)in_sizes; (void)n_in; (void)out_size; (void)ws_size;
  const float* f_atoms  = (const float*)d_in[0];
  const float* f_bonds  = (const float*)d_in[1];
  const int*   a2b      = (const int*)d_in[2];
  const int*   b2a      = (const int*)d_in[3];
  const int*   b2revb   = (const int*)d_in[4];
  const float* W_i_atom = (const float*)d_in[5];
  const float* W_i_bond = (const float*)d_in[6];
  const float* W_h      = (const float*)d_in[7];
  const float* W_lr     = (const float*)d_in[8];
  const float* W_o      = (const float*)d_in[9];
  const float* b_o      = (const float*)d_in[10];
  const float* gru_bias = (const float*)d_in[11];
  const float* w_ih_f   = (const float*)d_in[12];
  const float* w_hh_f   = (const float*)d_in[13];
  const float* b_ih_f   = (const float*)d_in[14];
  const float* b_hh_f   = (const float*)d_in[15];
  const float* w_ih_b   = (const float*)d_in[16];
  const float* w_hh_b   = (const float*)d_in[17];
  const float* b_ih_b   = (const float*)d_in[18];
  const float* b_hh_b   = (const float*)d_in[19];

  float* ws = (float*)d_ws;
  const size_t SZ_B = (size_t)NBd * H;  // 19,661,100
  const size_t SZ_A = (size_t)NAt * H;  //  4,915,500

  float* ib  = ws;
  float* mb0 = ws + SZ_B;
  float* mb1 = ws + 2 * SZ_B;
  float* ma  = ws + 3 * SZ_B;
  // late-phase aliases (all reuse regions dead by the time they're written)
  float* xgf     = ib;                        // 14,745,600
  float* message = mb0;                       //  9,831,000
  float* h0      = mb0 + 9831000;             //     76,800
  float* wTf     = h0 + (size_t)NM * H;       //    270,000
  float* wTb     = wTf + (size_t)H * H3;      //    270,000
  float* hbuf    = wTb + (size_t)H * H3;      //    307,200
  float* gbuf    = hbuf + (size_t)4 * NM * H; //    921,600
  float* aggb    = mb1;                       //  4,915,500
  float* node    = mb1 + SZ_A;                //  4,915,500
  float* iat     = mb1 + 2 * SZ_A;            //  4,915,500 (recomputed input_atom)
  float* msg     = mb1 + 14745600;            //  4,915,500 (exactly fills mb1 tail)
  float* xgb     = mb1;                       // 14,745,600 (after aggb/node/iat dead)
  float* ah      = ma;                        //  4,915,500 (after ma dead)

  dim3 blk(256);
  auto gg = [](int M, int N) {
    return dim3((unsigned)((N + 319) / 320), (unsigned)((M + 63) / 64));
  };
  const int gA = (int)((SZ_A + 255) / 256);

  // ma = input_atom = relu(f_atoms @ W_i_atom)
  gemm_mfma2<false,false,true,false,false,false><<<gg(NAt, H), blk, 0, stream>>>(
      f_atoms, nullptr, nullptr, nullptr, nullptr, W_i_atom, ma, nullptr, nullptr, nullptr,
      NAt, H, 133, 133, H, H);
  // ib = input_bond = relu(f_bonds @ W_i_bond); mb0 = copy
  gemm_mfma2<false,false,true,false,false,true><<<gg(NBd, H), blk, 0, stream>>>(
      f_bonds, nullptr, nullptr, nullptr, nullptr, W_i_bond, ib, mb0, nullptr, nullptr,
      NBd, H, 147, 147, H, H);

  // message passing depth loop (ping-pong mb0<->mb1, bond update fused into A-gather)
  float* mbp[2] = {mb0, mb1};
  int cur = 0;
  for (int d = 0; d < 4; d++) {
    agg_kernel<true><<<gA, blk, 0, stream>>>(mbp[cur], a2b, ma);
    gemm_mfma2<true,false,true,true,false,false><<<gg(NBd, H), blk, 0, stream>>>(
        ma, mbp[cur], nullptr, b2a, b2revb, W_h + (size_t)d * H * H,
        mbp[1 - cur], nullptr, ib, nullptr, NBd, H, H, H, H, H);
    cur ^= 1;
  }
  // cur == 0 again: final message_bond is in mb0
  agg_kernel<false><<<gA, blk, 0, stream>>>(mb0, a2b, aggb);

  // iat = recomputed input_atom (ma was updated in-place by the depth loop)
  gemm_mfma2<false,false,true,false,false,false><<<gg(NAt, H), blk, 0, stream>>>(
      f_atoms, nullptr, nullptr, nullptr, nullptr, W_i_atom, iat, nullptr, nullptr, nullptr,
      NAt, H, 133, 133, H, H);
  // node = [aggb | ma | iat] @ W_lr  (single K=900 CONCAT3 GEMM)
  gemm_mfma2<false,false,false,false,true,false><<<gg(NAt, H), blk, 0, stream>>>(
      aggb, ma, iat, nullptr, nullptr, W_lr, node, nullptr, nullptr, nullptr,
      NAt, H, 900, H, H, H);

  h0_kernel<<<(NM * H + 255) / 256, blk, 0, stream>>>(node, h0);
  msg_kernel<<<gA, blk, 0, stream>>>(node, gru_bias, msg);

  // GRU input gates: xg = xs @ w_ih^T + b_ih  (pre-transpose w_ih -> [K][N])
  const int gT = (H * H3 + 255) / 256;
  transpose_kernel<<<gT, blk, 0, stream>>>(w_ih_f, wTf);
  transpose_kernel<<<gT, blk, 0, stream>>>(w_ih_b, wTb);
  gemm_mfma2<false,true,false,false,false,false><<<gg(16384, H3), blk, 0, stream>>>(
      msg + H, nullptr, nullptr, nullptr, nullptr, wTf, xgf, nullptr, nullptr, b_ih_f,
      16384, H3, H, H, H3, H3);
  gemm_mfma2<false,true,false,false,false,false><<<gg(16384, H3), blk, 0, stream>>>(
      msg + H, nullptr, nullptr, nullptr, nullptr, wTb, xgb, nullptr, nullptr, b_ih_b,
      16384, H3, H, H, H3, H3);

  // sequential bidirectional GRU: 65 step launches (step 64 = final update only)
  for (int s = 0; s <= 64; s++) {
    gru_step_kernel<<<256, blk, 0, stream>>>(
        xgf, xgb, w_hh_f, w_hh_b, b_hh_f, b_hh_b, h0, hbuf, gbuf, message, s);
  }
  row0_kernel<<<3, blk, 0, stream>>>(msg, message);

  // readout
  gemm_mfma2<false,true,true,false,false,false><<<gg(NAt, H), blk, 0, stream>>>(
      message, nullptr, nullptr, nullptr, nullptr, W_o, ah, nullptr, nullptr, b_o,
      NAt, H, 600, 600, H, H);
  mean_kernel<<<(NM * H + 255) / 256, blk, 0, stream>>>(ah, (float*)d_out);
}

// Round 6
// 4377.403 us; speedup vs baseline: 1.5164x; 1.1156x over previous
//
#include <hip/hip_runtime.h>
#include <math.h>

#define H 300
#define H3 900
#define NAt 16385
#define NBd 65537
#define NM 256
#define APM 64

typedef __attribute__((ext_vector_type(8))) short bf16x8;
typedef __attribute__((ext_vector_type(4))) float f32x4;

__device__ __forceinline__ unsigned bf16_rne(float x) {
  unsigned u = __float_as_uint(x);
  return (u + 0x7fffu + ((u >> 16) & 1u)) >> 16;
}
__device__ __forceinline__ float bf16_up(unsigned h) {
  return __uint_as_float(h << 16);
}
// 3-way split: x ~= h + m + l (each bf16), residual ~2^-26 |x|
__device__ __forceinline__ void split3(float x, unsigned &h, unsigned &m, unsigned &l) {
  h = bf16_rne(x);
  float r1 = x - bf16_up(h);
  m = bf16_rne(r1);
  float r2 = r1 - bf16_up(m);
  l = bf16_rne(r2);
}
__device__ __forceinline__ void pack8(const unsigned* v, uint4 &o) {
  o.x = v[0] | (v[1] << 16); o.y = v[2] | (v[3] << 16);
  o.z = v[4] | (v[5] << 16); o.w = v[6] | (v[7] << 16);
}

// ======================= weight pre-split =======================
// B_logical[K][N] -> 3 bf16 planes in MFMA fragment-granule order.
// granule g = (kt*NT + t)*64 + lane holds n = t*16+(lane&15),
// k = kt*32 + (lane>>4)*8 + j (8 bf16, k-major). plane p at offset p*KT*NT*64.
// TRANS: B_logical[k][n] = W[n][k] (fused transpose for w_ih).
template<bool TRANS>
__global__ __launch_bounds__(256) void prep_split_kernel(
    const float* __restrict__ B, uint4* __restrict__ out,
    int K, int N, int ldb, int KT, int NT)
{
  int g = blockIdx.x * 256 + threadIdx.x;
  int total = KT * NT * 64;
  if (g >= total) return;
  int lane = g & 63;
  int t = (g >> 6) % NT;
  int kt = (g >> 6) / NT;
  int n = t * 16 + (lane & 15);
  int kb = kt * 32 + ((lane >> 4) << 3);
  float x[8];
#pragma unroll
  for (int j = 0; j < 8; j++) {
    int gk = kb + j;
    float v = 0.f;
    if (n < N && gk < K)
      v = TRANS ? B[(size_t)n * ldb + gk] : B[(size_t)gk * ldb + n];
    x[j] = v;
  }
  unsigned h[8], m[8], l[8];
#pragma unroll
  for (int j = 0; j < 8; j++) split3(x[j], h[j], m[j], l[j]);
  uint4 hv, mv, lv;
  pack8(h, hv); pack8(m, mv); pack8(l, lv);
  out[g] = hv;
  out[total + g] = mv;
  out[2 * total + g] = lv;
}

// ============== split-bf16 MFMA GEMM v3: pre-split B, A-only LDS ==============
// BM=64, BN=320 (up to 20 n-tiles/block). 4 waves: wave w owns n-tiles
// [5w,5w+5), all 4 m-tiles. B fragments loaded global->VGPR from pre-split
// planes (no VALU, no LDS). A staged in 2x-buffered LDS (split3 in-kernel).
template<bool ADDMAT, bool BIAS, bool RELU, bool GATHER, bool CONCAT, bool W2>
__global__ __launch_bounds__(256, 3) void gemm_mfma3(
    const float* __restrict__ A, const float* __restrict__ A2,
    const float* __restrict__ A3,
    const int* __restrict__ idx1, const int* __restrict__ idx2,
    const uint4* __restrict__ Bs,
    float* __restrict__ C, float* __restrict__ C2,
    const float* __restrict__ D, const float* __restrict__ bias,
    int M, int N, int K, int lda, int ldc, int KT, int NT)
{
  __shared__ uint4 sA[2][3][256];
  const int tid = threadIdx.x;
  const int lane = tid & 63;
  const int wid = tid >> 6;
  const int m0 = blockIdx.y * 64;
  const int tb = blockIdx.x * 20;
  int NTloc = NT - tb;
  if (NTloc > 20) NTloc = 20;

  const int a_row = m0 + (wid << 4) + (lane & 15);
  const int a_koct = lane >> 4;
  const bool arok = a_row < M;
  const float* Ap = nullptr;
  const float* Ap2 = nullptr;
  const float* Ap3 = nullptr;
  if constexpr (GATHER) {
    int i1 = arok ? idx1[a_row] : 0;
    int i2 = arok ? idx2[a_row] : 0;
    Ap  = A  + (size_t)i1 * lda;
    Ap2 = A2 + (size_t)i2 * lda;
  } else if constexpr (CONCAT) {
    int r = arok ? a_row : 0;
    Ap  = A  + (size_t)r * lda;
    Ap2 = A2 + (size_t)r * lda;
    Ap3 = A3 + (size_t)r * lda;
  } else {
    Ap = A + (size_t)(arok ? a_row : 0) * lda;
  }

  const int PS = KT * NT * 64;  // plane stride (uint4 units)

  f32x4 acc[4][5];
#pragma unroll
  for (int i = 0; i < 4; i++)
#pragma unroll
    for (int j = 0; j < 5; j++) acc[i][j] = (f32x4){0.f, 0.f, 0.f, 0.f};

  float ax[8];
  auto loadA = [&](int kt_) {
#pragma unroll
    for (int j = 0; j < 8; j++) {
      int gk = (kt_ << 5) + (a_koct << 3) + j;
      float v = 0.f;
      if (arok && gk < K) {
        if constexpr (GATHER) {
          v = Ap[gk] - Ap2[gk];
        } else if constexpr (CONCAT) {
          int s_ = (gk >= 2 * lda) ? 2 : ((gk >= lda) ? 1 : 0);
          int col = gk - s_ * lda;
          const float* src = (s_ == 0) ? Ap : ((s_ == 1) ? Ap2 : Ap3);
          v = src[col];
        } else {
          v = Ap[gk];
        }
      }
      ax[j] = v;
    }
  };
  auto writeA = [&](int slot) {
    unsigned h[8], m[8], l[8];
#pragma unroll
    for (int j = 0; j < 8; j++) split3(ax[j], h[j], m[j], l[j]);
    uint4 hv, mv, lv;
    pack8(h, hv); pack8(m, mv); pack8(l, lv);
    const int fi = (wid << 6) | lane;
    sA[slot][0][fi] = hv; sA[slot][1][fi] = mv; sA[slot][2][fi] = lv;
  };

  loadA(0);
  writeA(0);
  __syncthreads();

  for (int kt = 0; kt < KT; kt++) {
    const int cur = kt & 1;
    const bool more = kt + 1 < KT;
    if (more) loadA(kt + 1);
    bf16x8 aF[3][4];
#pragma unroll
    for (int p = 0; p < 3; p++)
#pragma unroll
      for (int i = 0; i < 4; i++)
        aF[p][i] = ((const bf16x8*)sA[cur][p])[(i << 6) | lane];
    const int bk = kt * NT * 64 + lane;
#pragma unroll
    for (int j = 0; j < 5; j++) {
      const int t = wid * 5 + j;
      if (t < NTloc) {
        const int gidx = bk + (tb + t) * 64;
        bf16x8 b0 = ((const bf16x8*)Bs)[gidx];
        bf16x8 b1 = ((const bf16x8*)Bs)[gidx + PS];
        bf16x8 b2 = ((const bf16x8*)Bs)[gidx + 2 * PS];
#pragma unroll
        for (int i = 0; i < 4; i++) {
          acc[i][j] = __builtin_amdgcn_mfma_f32_16x16x32_bf16(aF[2][i], b0, acc[i][j], 0, 0, 0);
          acc[i][j] = __builtin_amdgcn_mfma_f32_16x16x32_bf16(aF[0][i], b2, acc[i][j], 0, 0, 0);
          acc[i][j] = __builtin_amdgcn_mfma_f32_16x16x32_bf16(aF[1][i], b1, acc[i][j], 0, 0, 0);
          acc[i][j] = __builtin_amdgcn_mfma_f32_16x16x32_bf16(aF[1][i], b0, acc[i][j], 0, 0, 0);
          acc[i][j] = __builtin_amdgcn_mfma_f32_16x16x32_bf16(aF[0][i], b1, acc[i][j], 0, 0, 0);
          acc[i][j] = __builtin_amdgcn_mfma_f32_16x16x32_bf16(aF[0][i], b0, acc[i][j], 0, 0, 0);
        }
      }
    }
    if (more) writeA(cur ^ 1);
    __syncthreads();
  }

  // epilogue: C/D layout col=lane&15, row=(lane>>4)*4+r
  const int cr = (lane >> 4) << 2;
  const int cc = lane & 15;
#pragma unroll
  for (int j = 0; j < 5; j++) {
    const int t = wid * 5 + j;
    if (t >= NTloc) break;
    const int gn = ((tb + t) << 4) + cc;
    if (gn >= N) continue;
#pragma unroll
    for (int i = 0; i < 4; i++) {
#pragma unroll
      for (int r = 0; r < 4; r++) {
        const int gm = m0 + (i << 4) + cr + r;
        if (gm >= M) continue;
        const size_t rowoff = (size_t)gm * ldc;
        float v = acc[i][j][r];
        if constexpr (ADDMAT) v += D[rowoff + gn];
        if constexpr (BIAS) v += bias[gn];
        if constexpr (RELU) v = fmaxf(v, 0.f);
        C[rowoff + gn] = v;
        if constexpr (W2) C2[rowoff + gn] = v;
      }
    }
  }
}

// ============== round-5 GEMM (fallback when ws lacks pre-split slack) ==============
template<bool ADDMAT, bool BIAS, bool RELU, bool GATHER, bool CONCAT, bool W2>
__global__ __launch_bounds__(256, 2) void gemm_mfma2(
    const float* __restrict__ A, const float* __restrict__ A2,
    const float* __restrict__ A3,
    const int* __restrict__ idx1, const int* __restrict__ idx2,
    const float* __restrict__ B,
    float* __restrict__ C, float* __restrict__ C2,
    const float* __restrict__ D, const float* __restrict__ bias,
    int M, int N, int K, int lda, int ldb, int ldc)
{
  __shared__ uint4 sA[3][256];
  __shared__ uint4 sB[3][1280];
  const int tid = threadIdx.x;
  const int lane = tid & 63;
  const int wid = tid >> 6;
  const int m0 = blockIdx.y * 64;
  const int n0 = blockIdx.x * 320;
  int NTloc = (N - n0 + 15) >> 4;
  if (NTloc > 20) NTloc = 20;

  const int a_row = m0 + (wid << 4) + (lane & 15);
  const int a_koct = lane >> 4;
  const bool arok = a_row < M;
  const float* Ap = nullptr;
  const float* Ap2 = nullptr;
  const float* Ap3 = nullptr;
  if constexpr (GATHER) {
    int i1 = arok ? idx1[a_row] : 0;
    int i2 = arok ? idx2[a_row] : 0;
    Ap  = A  + (size_t)i1 * lda;
    Ap2 = A2 + (size_t)i2 * lda;
  } else if constexpr (CONCAT) {
    int r = arok ? a_row : 0;
    Ap  = A  + (size_t)r * lda;
    Ap2 = A2 + (size_t)r * lda;
    Ap3 = A3 + (size_t)r * lda;
  } else {
    Ap = A + (size_t)(arok ? a_row : 0) * lda;
  }

  f32x4 acc[4][5];
#pragma unroll
  for (int i = 0; i < 4; i++)
#pragma unroll
    for (int j = 0; j < 5; j++) acc[i][j] = (f32x4){0.f, 0.f, 0.f, 0.f};

  const int KT = (K + 31) >> 5;
  for (int kt = 0; kt < KT; kt++) {
    const int kb0 = kt << 5;
    {
      const int kb = kb0 + a_koct * 8;
      float x[8];
#pragma unroll
      for (int j = 0; j < 8; j++) {
        int gk = kb + j;
        float v = 0.f;
        if (arok && gk < K) {
          if constexpr (GATHER) {
            v = Ap[gk] - Ap2[gk];
          } else if constexpr (CONCAT) {
            int s_ = (gk >= 2 * lda) ? 2 : ((gk >= lda) ? 1 : 0);
            int col = gk - s_ * lda;
            const float* src = (s_ == 0) ? Ap : ((s_ == 1) ? Ap2 : Ap3);
            v = src[col];
          } else {
            v = Ap[gk];
          }
        }
        x[j] = v;
      }
      unsigned h[8], mv_[8], l[8];
#pragma unroll
      for (int j = 0; j < 8; j++) split3(x[j], h[j], mv_[j], l[j]);
      uint4 hv, mv, lv;
      pack8(h, hv); pack8(mv_, mv); pack8(l, lv);
      const int fi = (wid << 6) | lane;
      sA[0][fi] = hv; sA[1][fi] = mv; sA[2][fi] = lv;
    }
#pragma unroll
    for (int i = 0; i < 5; i++) {
      const int g = tid + (i << 8);
      const int t = g >> 6;
      if (t < NTloc) {
        const int gl = g & 63;
        const int n = n0 + (t << 4) + (gl & 15);
        const int kb = kb0 + ((gl >> 4) << 3);
        float x[8];
#pragma unroll
        for (int j = 0; j < 8; j++) {
          int gk = kb + j;
          x[j] = (n < N && gk < K) ? B[(size_t)gk * ldb + n] : 0.f;
        }
        unsigned h[8], mv_[8], l[8];
#pragma unroll
        for (int j = 0; j < 8; j++) split3(x[j], h[j], mv_[j], l[j]);
        uint4 hv, mv, lv;
        pack8(h, hv); pack8(mv_, mv); pack8(l, lv);
        sB[0][g] = hv; sB[1][g] = mv; sB[2][g] = lv;
      }
    }
    __syncthreads();
    bf16x8 aF[3][4];
#pragma unroll
    for (int p = 0; p < 3; p++)
#pragma unroll
      for (int i = 0; i < 4; i++)
        aF[p][i] = ((const bf16x8*)sA[p])[(i << 6) | lane];
#pragma unroll
    for (int j = 0; j < 5; j++) {
      const int t = wid * 5 + j;
      if (t < NTloc) {
        const int fi = (t << 6) | lane;
        bf16x8 b0 = ((const bf16x8*)sB[0])[fi];
        bf16x8 b1 = ((const bf16x8*)sB[1])[fi];
        bf16x8 b2 = ((const bf16x8*)sB[2])[fi];
#pragma unroll
        for (int i = 0; i < 4; i++) {
          acc[i][j] = __builtin_amdgcn_mfma_f32_16x16x32_bf16(aF[2][i], b0, acc[i][j], 0, 0, 0);
          acc[i][j] = __builtin_amdgcn_mfma_f32_16x16x32_bf16(aF[0][i], b2, acc[i][j], 0, 0, 0);
          acc[i][j] = __builtin_amdgcn_mfma_f32_16x16x32_bf16(aF[1][i], b1, acc[i][j], 0, 0, 0);
          acc[i][j] = __builtin_amdgcn_mfma_f32_16x16x32_bf16(aF[1][i], b0, acc[i][j], 0, 0, 0);
          acc[i][j] = __builtin_amdgcn_mfma_f32_16x16x32_bf16(aF[0][i], b1, acc[i][j], 0, 0, 0);
          acc[i][j] = __builtin_amdgcn_mfma_f32_16x16x32_bf16(aF[0][i], b0, acc[i][j], 0, 0, 0);
        }
      }
    }
    __syncthreads();
  }

  const int cr = (lane >> 4) << 2;
  const int cc = lane & 15;
#pragma unroll
  for (int j = 0; j < 5; j++) {
    const int t = wid * 5 + j;
    if (t >= NTloc) break;
    const int gn = n0 + (t << 4) + cc;
    if (gn >= N) continue;
#pragma unroll
    for (int i = 0; i < 4; i++) {
#pragma unroll
      for (int r = 0; r < 4; r++) {
        const int gm = m0 + (i << 4) + cr + r;
        if (gm >= M) continue;
        const size_t rowoff = (size_t)gm * ldc;
        float v = acc[i][j][r];
        if constexpr (ADDMAT) v += D[rowoff + gn];
        if constexpr (BIAS) v += bias[gn];
        if constexpr (RELU) v = fmaxf(v, 0.f);
        C[rowoff + gn] = v;
        if constexpr (W2) C2[rowoff + gn] = v;
      }
    }
  }
}

// ======================= neighbor aggregation: sum * max over 6 =======================
template<bool UPDATE>
__global__ __launch_bounds__(256) void agg_kernel(
    const float* __restrict__ message_bond, const int* __restrict__ a2b,
    float* __restrict__ out)
{
  int gid = blockIdx.x * 256 + threadIdx.x;
  if (gid >= NAt * H) return;
  int a = gid / H;
  int hh = gid - a * H;
  const int* ab = a2b + (size_t)a * 6;
  float s = 0.f, mx = -3.0e38f;
#pragma unroll
  for (int j = 0; j < 6; j++) {
    float v = message_bond[(size_t)ab[j] * H + hh];
    s += v;
    mx = fmaxf(mx, v);
  }
  float agg = s * mx;
  if (UPDATE) out[gid] += agg;
  else out[gid] = agg;
}

// ======================= misc elementwise =======================
__global__ __launch_bounds__(256) void msg_kernel(
    const float* __restrict__ node, const float* __restrict__ gru_bias,
    float* __restrict__ msg)
{
  int gid = blockIdx.x * 256 + threadIdx.x;
  if (gid >= NAt * H) return;
  int hh = gid % H;
  msg[gid] = fmaxf(node[gid] + gru_bias[hh], 0.f);
}

__global__ __launch_bounds__(256) void h0_kernel(
    const float* __restrict__ node, float* __restrict__ h0)
{
  int gid = blockIdx.x * 256 + threadIdx.x;
  if (gid >= NM * H) return;
  int m = gid / H;
  int hh = gid - m * H;
  const float* base = node + ((size_t)(1 + m * APM)) * H + hh;
  float mx = base[0];
  for (int t = 1; t < APM; t++) mx = fmaxf(mx, base[(size_t)t * H]);
  h0[gid] = mx;
}

__global__ __launch_bounds__(256) void transpose_kernel(
    const float* __restrict__ w, float* __restrict__ wT)
{
  int gid = blockIdx.x * 256 + threadIdx.x;
  if (gid >= H * H3) return;
  int k = gid / H3;
  int g = gid - k * H3;
  wT[gid] = w[(size_t)g * H + k];
}

__global__ __launch_bounds__(256) void row0_kernel(
    const float* __restrict__ msg, float* __restrict__ message)
{
  int gid = blockIdx.x * 256 + threadIdx.x;
  if (gid >= 2 * H) return;
  message[gid] = msg[gid % H];
}

__global__ __launch_bounds__(256) void mean_kernel(
    const float* __restrict__ ah, float* __restrict__ out)
{
  int gid = blockIdx.x * 256 + threadIdx.x;
  if (gid >= NM * H) return;
  int m = gid / H;
  int hh = gid - m * H;
  const float* base = ah + ((size_t)(1 + m * APM)) * H + hh;
  float s = 0.f;
#pragma unroll 8
  for (int t = 0; t < APM; t++) s += base[(size_t)t * H];
  out[gid] = s * (1.f / APM);
}

// ======================= GRU step =======================
__global__ __launch_bounds__(256) void gru_step_kernel(
    const float* __restrict__ xg_f, const float* __restrict__ xg_b,
    const float* __restrict__ w_hh_f, const float* __restrict__ w_hh_b,
    const float* __restrict__ b_hh_f, const float* __restrict__ b_hh_b,
    const float* __restrict__ h0,
    float* __restrict__ h_buf,   // [2][2][NM][H]
    float* __restrict__ g_buf,   // [2][2][NM][H3]
    float* __restrict__ message, // [NAt][600]
    int s)
{
  __shared__ float h_lds[8 * H];
  const int tid = threadIdx.x;
  const int b = blockIdx.x;
  const int ct = b & 3;
  const int mg = (b >> 2) & 31;
  const int dir = b >> 7;
  const int r = s & 1;
  const int w = 1 - r;
  const float* xg = dir ? xg_b : xg_f;
  const float* whh = dir ? w_hh_b : w_hh_f;
  const float* bhh = dir ? b_hh_b : b_hh_f;
  const float* hb_r = h_buf + ((size_t)(r * 2 + dir)) * NM * H;
  float* hb_w = h_buf + ((size_t)(w * 2 + dir)) * NM * H;
  const float* gb_r = g_buf + ((size_t)(r * 2 + dir)) * NM * H3;
  float* gb_w = g_buf + ((size_t)(w * 2 + dir)) * NM * H3;

  int t_prev = 0;
  if (s > 0) t_prev = dir ? (64 - s) : (s - 1);

  for (int i = tid; i < 8 * H; i += 256) {
    int m = i / H;
    int hh = i - m * H;
    int mol = mg * 8 + m;
    float hc;
    if (s == 0) {
      hc = h0[(size_t)mol * H + hh];
    } else {
      const float* xr = xg + ((size_t)(mol * 64 + t_prev)) * H3;
      float ir = xr[hh], iz = xr[H + hh], inn = xr[2 * H + hh];
      const float* gp = gb_r + (size_t)mol * H3;
      float hr = gp[hh], hz = gp[H + hh], hn = gp[2 * H + hh];
      float hp = hb_r[(size_t)mol * H + hh];
      float rr = 1.f / (1.f + expf(-(ir + hr)));
      float zz = 1.f / (1.f + expf(-(iz + hz)));
      float nn = tanhf(inn + rr * hn);
      hc = (1.f - zz) * nn + zz * hp;
    }
    h_lds[i] = hc;
    if (ct == 0) {
      hb_w[(size_t)mol * H + hh] = hc;
      if (s > 0) {
        int row = 1 + mol * 64 + t_prev;
        message[(size_t)row * 600 + dir * H + hh] = hc;
      }
    }
  }
  __syncthreads();
  if (s >= 64) return;

  for (int i = tid; i < 8 * 225; i += 256) {
    int m = i & 7;
    int gl = i >> 3;
    int g = ct * 225 + gl;
    const float4* wr4 = (const float4*)(whh + (size_t)g * H);
    const float4* hl4 = (const float4*)(h_lds + m * H);
    float acc = bhh[g];
#pragma unroll 5
    for (int k = 0; k < H / 4; k++) {
      float4 wv = wr4[k];
      float4 hv = hl4[k];
      acc += wv.x * hv.x + wv.y * hv.y + wv.z * hv.z + wv.w * hv.w;
    }
    int mol = mg * 8 + m;
    gb_w[(size_t)mol * H3 + g] = acc;
  }
}

// ======================= host =======================
// Base layout (floats), 63,898,800 = 255.6 MB; pre-split weights (2,305,536
// floats = 9.2 MB) appended at tail iff ws_size permits (runtime-constant).
extern "C" void kernel_launch(void* const* d_in, const int* in_sizes, int n_in,
                              void* d_out, int out_size, void* d_ws, size_t ws_size,
                              hipStream_t stream) {
  (void)in_sizes; (void)n_in; (void)out_size;
  const float* f_atoms  = (const float*)d_in[0];
  const float* f_bonds  = (const float*)d_in[1];
  const int*   a2b      = (const int*)d_in[2];
  const int*   b2a      = (const int*)d_in[3];
  const int*   b2revb   = (const int*)d_in[4];
  const float* W_i_atom = (const float*)d_in[5];
  const float* W_i_bond = (const float*)d_in[6];
  const float* W_h      = (const float*)d_in[7];
  const float* W_lr     = (const float*)d_in[8];
  const float* W_o      = (const float*)d_in[9];
  const float* b_o      = (const float*)d_in[10];
  const float* gru_bias = (const float*)d_in[11];
  const float* w_ih_f   = (const float*)d_in[12];
  const float* w_hh_f   = (const float*)d_in[13];
  const float* b_ih_f   = (const float*)d_in[14];
  const float* b_hh_f   = (const float*)d_in[15];
  const float* w_ih_b   = (const float*)d_in[16];
  const float* w_hh_b   = (const float*)d_in[17];
  const float* b_ih_b   = (const float*)d_in[18];
  const float* b_hh_b   = (const float*)d_in[19];

  float* ws = (float*)d_ws;
  const size_t SZ_B = (size_t)NBd * H;  // 19,661,100
  const size_t SZ_A = (size_t)NAt * H;  //  4,915,500

  float* ib  = ws;
  float* mb0 = ws + SZ_B;
  float* mb1 = ws + 2 * SZ_B;
  float* ma  = ws + 3 * SZ_B;
  float* xgf     = ib;
  float* message = mb0;
  float* h0      = mb0 + 9831000;
  float* wTf     = h0 + (size_t)NM * H;
  float* wTb     = wTf + (size_t)H * H3;
  float* hbuf    = wTb + (size_t)H * H3;
  float* gbuf    = hbuf + (size_t)4 * NM * H;
  float* aggb    = mb1;
  float* node    = mb1 + SZ_A;
  float* iat     = mb1 + 2 * SZ_A;
  float* msg     = mb1 + 14745600;
  float* xgb     = mb1;
  float* ah      = ma;

  // pre-split weight region at tail (uint4 granule offsets)
  const size_t BASE_FLOATS = 63898800;
  uint4* wsp = (uint4*)(ws + BASE_FLOATS);
  const int G_IA = 5 * 19 * 64;    // 6080
  const int G_IB = 5 * 19 * 64;    // 6080
  const int G_WH = 10 * 19 * 64;   // 12160
  const int G_LR = 29 * 19 * 64;   // 35264
  const int G_WT = 10 * 57 * 64;   // 36480
  const int G_WO = 19 * 19 * 64;   // 23104
  uint4* sp_ia = wsp;
  uint4* sp_ib = sp_ia + 3 * G_IA;
  uint4* sp_wh = sp_ib + 3 * G_IB;           // 4 consecutive, 3*G_WH each
  uint4* sp_lr = sp_wh + 4 * 3 * G_WH;
  uint4* sp_tf = sp_lr + 3 * G_LR;
  uint4* sp_tb = sp_tf + 3 * G_WT;
  uint4* sp_wo = sp_tb + 3 * G_WT;
  const size_t NEED_BYTES = (BASE_FLOATS + 2305536) * 4;  // 264,817,344
  const bool presplit = ws_size >= NEED_BYTES;

  dim3 blk(256);
  auto gg3 = [](int M, int NT) {
    return dim3((unsigned)((NT + 19) / 20), (unsigned)((M + 63) / 64));
  };
  auto gg2 = [](int M, int N) {
    return dim3((unsigned)((N + 319) / 320), (unsigned)((M + 63) / 64));
  };
  auto pg = [](int gran) { return dim3((unsigned)((gran + 255) / 256)); };
  const int gA = (int)((SZ_A + 255) / 256);

  if (presplit) {
    // ---- weight prep (once per launch; all independent) ----
    prep_split_kernel<false><<<pg(G_IA), blk, 0, stream>>>(W_i_atom, sp_ia, 133, 300, 300, 5, 19);
    prep_split_kernel<false><<<pg(G_IB), blk, 0, stream>>>(W_i_bond, sp_ib, 147, 300, 300, 5, 19);
    for (int d = 0; d < 4; d++)
      prep_split_kernel<false><<<pg(G_WH), blk, 0, stream>>>(
          W_h + (size_t)d * H * H, sp_wh + (size_t)d * 3 * G_WH, 300, 300, 300, 10, 19);
    prep_split_kernel<false><<<pg(G_LR), blk, 0, stream>>>(W_lr, sp_lr, 900, 300, 300, 29, 19);
    prep_split_kernel<true><<<pg(G_WT), blk, 0, stream>>>(w_ih_f, sp_tf, 300, 900, 300, 10, 57);
    prep_split_kernel<true><<<pg(G_WT), blk, 0, stream>>>(w_ih_b, sp_tb, 300, 900, 300, 10, 57);
    prep_split_kernel<false><<<pg(G_WO), blk, 0, stream>>>(W_o, sp_wo, 600, 300, 300, 19, 19);

    // ma = relu(f_atoms @ W_i_atom)
    gemm_mfma3<false,false,true,false,false,false><<<gg3(NAt, 19), blk, 0, stream>>>(
        f_atoms, nullptr, nullptr, nullptr, nullptr, sp_ia, ma, nullptr, nullptr, nullptr,
        NAt, H, 133, 133, H, 5, 19);
    // ib = relu(f_bonds @ W_i_bond); mb0 = copy
    gemm_mfma3<false,false,true,false,false,true><<<gg3(NBd, 19), blk, 0, stream>>>(
        f_bonds, nullptr, nullptr, nullptr, nullptr, sp_ib, ib, mb0, nullptr, nullptr,
        NBd, H, 147, 147, H, 5, 19);

    float* mbp[2] = {mb0, mb1};
    int cur = 0;
    for (int d = 0; d < 4; d++) {
      agg_kernel<true><<<gA, blk, 0, stream>>>(mbp[cur], a2b, ma);
      gemm_mfma3<true,false,true,true,false,false><<<gg3(NBd, 19), blk, 0, stream>>>(
          ma, mbp[cur], nullptr, b2a, b2revb, sp_wh + (size_t)d * 3 * G_WH,
          mbp[1 - cur], nullptr, ib, nullptr, NBd, H, H, H, H, 10, 19);
      cur ^= 1;
    }
    agg_kernel<false><<<gA, blk, 0, stream>>>(mb0, a2b, aggb);

    gemm_mfma3<false,false,true,false,false,false><<<gg3(NAt, 19), blk, 0, stream>>>(
        f_atoms, nullptr, nullptr, nullptr, nullptr, sp_ia, iat, nullptr, nullptr, nullptr,
        NAt, H, 133, 133, H, 5, 19);
    gemm_mfma3<false,false,false,false,true,false><<<gg3(NAt, 19), blk, 0, stream>>>(
        aggb, ma, iat, nullptr, nullptr, sp_lr, node, nullptr, nullptr, nullptr,
        NAt, H, 900, H, H, 29, 19);

    h0_kernel<<<(NM * H + 255) / 256, blk, 0, stream>>>(node, h0);
    msg_kernel<<<gA, blk, 0, stream>>>(node, gru_bias, msg);

    gemm_mfma3<false,true,false,false,false,false><<<gg3(16384, 57), blk, 0, stream>>>(
        msg + H, nullptr, nullptr, nullptr, nullptr, sp_tf, xgf, nullptr, nullptr, b_ih_f,
        16384, H3, H, H, H3, 10, 57);
    gemm_mfma3<false,true,false,false,false,false><<<gg3(16384, 57), blk, 0, stream>>>(
        msg + H, nullptr, nullptr, nullptr, nullptr, sp_tb, xgb, nullptr, nullptr, b_ih_b,
        16384, H3, H, H, H3, 10, 57);

    for (int s = 0; s <= 64; s++) {
      gru_step_kernel<<<256, blk, 0, stream>>>(
          xgf, xgb, w_hh_f, w_hh_b, b_hh_f, b_hh_b, h0, hbuf, gbuf, message, s);
    }
    row0_kernel<<<3, blk, 0, stream>>>(msg, message);

    gemm_mfma3<false,true,true,false,false,false><<<gg3(NAt, 19), blk, 0, stream>>>(
        message, nullptr, nullptr, nullptr, nullptr, sp_wo, ah, nullptr, nullptr, b_o,
        NAt, H, 600, 600, H, 19, 19);
    mean_kernel<<<(NM * H + 255) / 256, blk, 0, stream>>>(ah, (float*)d_out);
  } else {
    // ---- fallback: round-5 proven path ----
    gemm_mfma2<false,false,true,false,false,false><<<gg2(NAt, H), blk, 0, stream>>>(
        f_atoms, nullptr, nullptr, nullptr, nullptr, W_i_atom, ma, nullptr, nullptr, nullptr,
        NAt, H, 133, 133, H, H);
    gemm_mfma2<false,false,true,false,false,true><<<gg2(NBd, H), blk, 0, stream>>>(
        f_bonds, nullptr, nullptr, nullptr, nullptr, W_i_bond, ib, mb0, nullptr, nullptr,
        NBd, H, 147, 147, H, H);
    float* mbp[2] = {mb0, mb1};
    int cur = 0;
    for (int d = 0; d < 4; d++) {
      agg_kernel<true><<<gA, blk, 0, stream>>>(mbp[cur], a2b, ma);
      gemm_mfma2<true,false,true,true,false,false><<<gg2(NBd, H), blk, 0, stream>>>(
          ma, mbp[cur], nullptr, b2a, b2revb, W_h + (size_t)d * H * H,
          mbp[1 - cur], nullptr, ib, nullptr, NBd, H, H, H, H, H);
      cur ^= 1;
    }
    agg_kernel<false><<<gA, blk, 0, stream>>>(mb0, a2b, aggb);
    gemm_mfma2<false,false,true,false,false,false><<<gg2(NAt, H), blk, 0, stream>>>(
        f_atoms, nullptr, nullptr, nullptr, nullptr, W_i_atom, iat, nullptr, nullptr, nullptr,
        NAt, H, 133, 133, H, H);
    gemm_mfma2<false,false,false,false,true,false><<<gg2(NAt, H), blk, 0, stream>>>(
        aggb, ma, iat, nullptr, nullptr, W_lr, node, nullptr, nullptr, nullptr,
        NAt, H, 900, H, H, H);
    h0_kernel<<<(NM * H + 255) / 256, blk, 0, stream>>>(node, h0);
    msg_kernel<<<gA, blk, 0, stream>>>(node, gru_bias, msg);
    const int gT = (H * H3 + 255) / 256;
    transpose_kernel<<<gT, blk, 0, stream>>>(w_ih_f, wTf);
    transpose_kernel<<<gT, blk, 0, stream>>>(w_ih_b, wTb);
    gemm_mfma2<false,true,false,false,false,false><<<gg2(16384, H3), blk, 0, stream>>>(
        msg + H, nullptr, nullptr, nullptr, nullptr, wTf, xgf, nullptr, nullptr, b_ih_f,
        16384, H3, H, H, H3, H3);
    gemm_mfma2<false,true,false,false,false,false><<<gg2(16384, H3), blk, 0, stream>>>(
        msg + H, nullptr, nullptr, nullptr, nullptr, wTb, xgb, nullptr, nullptr, b_ih_b,
        16384, H3, H, H, H3, H3);
    for (int s = 0; s <= 64; s++) {
      gru_step_kernel<<<256, blk, 0, stream>>>(
          xgf, xgb, w_hh_f, w_hh_b, b_hh_f, b_hh_b, h0, hbuf, gbuf, message, s);
    }
    row0_kernel<<<3, blk, 0, stream>>>(msg, message);
    gemm_mfma2<false,true,true,false,false,false><<<gg2(NAt, H), blk, 0, stream>>>(
        message, nullptr, nullptr, nullptr, nullptr, W_o, ah, nullptr, nullptr, b_o,
        NAt, H, 600, 600, H, H);
    mean_kernel<<<(NM * H + 255) / 256, blk, 0, stream>>>(ah, (float*)d_out);
  }
}